// Round 6
// baseline (181.938 us; speedup 1.0000x reference)
//
#include <hip/hip_runtime.h>
#include <hip/hip_bf16.h>
#include <math.h>

typedef __attribute__((ext_vector_type(8))) short short8;
typedef __attribute__((ext_vector_type(4))) short s16x4;
typedef __attribute__((ext_vector_type(4))) float f32x4;

#define BB 4
#define HW 4096
#define CC 256
#define FC 64
#define L2E 1.4426950408889634f

// ws byte offsets
#define OFF_EMB   0                      // short[16384*64]   = 2 MB
#define OFF_SCT3  (2*1024*1024)          // short[4*64*4*16*64*4] = 8 MB
#define OFF_SQN   (OFF_SCT3 + 8*1024*1024)
#define OFF_T     (OFF_SQN + 65536)
#define OFF_D     (OFF_T   + 65536)
#define OFF_WEMB2 (OFF_D   + 65536)      // short[32*64*8] = 32 KB
#define OFF_WATT2 (OFF_WEMB2 + 32768)    // short[32*256*8] = 128 KB

static __device__ __forceinline__ short f2bf(float f) {
    __hip_bfloat16 h = __float2bfloat16(f);
    return *reinterpret_cast<short*>(&h);
}
static __device__ __forceinline__ float bf2f(short s) {
    __hip_bfloat16 h = *reinterpret_cast<__hip_bfloat16*>(&s);
    return __bfloat162float(h);
}
static __device__ __forceinline__ float fexp2(float x) {
#if __has_builtin(__builtin_amdgcn_exp2f)
    return __builtin_amdgcn_exp2f(x);
#else
    float r; asm("v_exp_f32 %0, %1" : "=v"(r) : "v"(x)); return r;
#endif
}
static __device__ __forceinline__ float frcp(float x) {
#if __has_builtin(__builtin_amdgcn_rcpf)
    return __builtin_amdgcn_rcpf(x);
#else
    return 1.0f / x;
#endif
}
// 16x16x16 bf16 MFMA (K=16): A,B = 4 bf16 (2 VGPR), C/D = 4 f32
static __device__ __forceinline__ f32x4 mfma16(s16x4 a, s16x4 b, f32x4 c) {
#if __has_builtin(__builtin_amdgcn_mfma_f32_16x16x16bf16_1k)
    return __builtin_amdgcn_mfma_f32_16x16x16bf16_1k(a, b, c, 0, 0, 0);
#else
    asm("v_mfma_f32_16x16x16_bf16 %0, %1, %2, %0" : "+v"(c) : "v"(a), "v"(b));
    return c;
#endif
}

// ---------------------------------------------------------------------------
// K0: weight conversion to tiled bf16 B-fragment layouts + D zero.
// ---------------------------------------------------------------------------
__global__ __launch_bounds__(256) void k_prep(const float* __restrict__ Wemb,
    const float* __restrict__ Watt, short* __restrict__ Wemb2,
    short* __restrict__ Watt2, float* __restrict__ D)
{
    const int bid = blockIdx.x, t = threadIdx.x;
    if (bid < 256) {
        Watt2[(size_t)(t>>3)*2048 + bid*8 + (t&7)] = f2bf(Watt[(size_t)bid*256 + t]);
        if (bid < 64) D[bid*256 + t] = 0.f;
    } else {
        const int f = bid - 256;
        Wemb2[(size_t)(t>>3)*512 + f*8 + (t&7)] = f2bf(Wemb[(size_t)f*256 + t]);
    }
}

// ---------------------------------------------------------------------------
// K1 (fused emb + shortcut + threshold, all MFMA). grid 1024 x 256.
// Writes sct3 lane-ordered: [b][jt][jq][nn16][lane64][e4], elem =
// sc[j = jt*64 + jq*16 + (lane>>4)*4 + e][ch = nn16*16 + (lane&15)].
// ---------------------------------------------------------------------------
__global__ __launch_bounds__(256) void k_front(const float* __restrict__ fm,
    const short* __restrict__ Wemb2, const short* __restrict__ Watt2,
    const float* __restrict__ bemb, const float* __restrict__ batt,
    const float* __restrict__ wthr, const float* __restrict__ bthr,
    short* __restrict__ emb, short* __restrict__ sct3,
    float* __restrict__ sqn, float* __restrict__ T)
{
    const int blk = blockIdx.x;
    const int b = blk >> 8;
    const int r0 = (blk & 255) * 16;
    const int t = threadIdx.x;
    const int w = t >> 6, lane = t & 63, g = lane >> 4, n16 = lane & 15;
    __shared__ short fmt[16*256];
    __shared__ float tred[16][4];
    __shared__ float qred[16][4];
    #pragma unroll
    for (int v = t; v < 512; v += 256) {
        const int row = v >> 5, c32 = v & 31;
        const float4* src = (const float4*)(fm + ((size_t)b*HW + r0 + row)*CC + c32*8);
        float4 x0 = src[0], x1 = src[1];
        short8 pv;
        pv[0]=f2bf(x0.x); pv[1]=f2bf(x0.y); pv[2]=f2bf(x0.z); pv[3]=f2bf(x0.w);
        pv[4]=f2bf(x1.x); pv[5]=f2bf(x1.y); pv[6]=f2bf(x1.z); pv[7]=f2bf(x1.w);
        *(short8*)((char*)fmt + row*512 + ((c32*16) ^ ((row&7)<<4))) = pv;
    }
    __syncthreads();
    const int cb = w*64, fb = w*16;
    f32x4 acc[4], acce;
    #pragma unroll
    for (int nn = 0; nn < 4; ++nn) acc[nn] = (f32x4){0.f,0.f,0.f,0.f};
    acce = (f32x4){0.f,0.f,0.f,0.f};
    #pragma unroll
    for (int kk = 0; kk < 8; ++kk) {
        const int kc = kk*4 + g;
        short8 a = *(const short8*)((const char*)fmt + n16*512 + ((kc*16) ^ ((n16&7)<<4)));
        const short* wb = Watt2 + (size_t)kc*2048 + (cb + n16)*8;
        #pragma unroll
        for (int nn = 0; nn < 4; ++nn) {
            short8 bv = *(const short8*)(wb + nn*128);
            acc[nn] = __builtin_amdgcn_mfma_f32_16x16x32_bf16(a, bv, acc[nn], 0, 0, 0);
        }
        short8 be = *(const short8*)(Wemb2 + (size_t)kc*512 + (fb + n16)*8);
        acce = __builtin_amdgcn_mfma_f32_16x16x32_bf16(a, be, acce, 0, 0, 0);
    }
    float tp[4] = {0.f,0.f,0.f,0.f};
    const int jt_ = r0 >> 6;
    const int jq_ = (r0 >> 4) & 3;
    #pragma unroll
    for (int nn = 0; nn < 4; ++nn) {
        const int ch = cb + nn*16 + n16;
        const float ba_ = batt[ch], wt_ = wthr[ch];
        s16x4 pk;
        #pragma unroll
        for (int r = 0; r < 4; ++r) {
            float v = acc[nn][r] + ba_;
            tp[r] = fmaf(v, wt_, tp[r]);
            pk[r] = f2bf(v);
        }
        *(s16x4*)(sct3 + ((((size_t)b*64 + jt_)*4 + jq_)*16 + (w*4 + nn))*256
                       + (size_t)(g*16 + n16)*4) = pk;
    }
    #pragma unroll
    for (int r = 0; r < 4; ++r)
        #pragma unroll
        for (int off = 1; off <= 8; off <<= 1) tp[r] += __shfl_xor(tp[r], off);
    const int f = fb + n16;
    const float be_ = bemb[f];
    float qp[4];
    #pragma unroll
    for (int r = 0; r < 4; ++r) {
        short bv = f2bf(acce[r] + be_);
        emb[((size_t)b*HW + r0 + g*4 + r)*FC + f] = bv;
        float ef = bf2f(bv);
        qp[r] = ef*ef;
        #pragma unroll
        for (int off = 1; off <= 8; off <<= 1) qp[r] += __shfl_xor(qp[r], off);
    }
    if (n16 == 0) {
        #pragma unroll
        for (int r = 0; r < 4; ++r) { tred[g*4+r][w] = tp[r]; qred[g*4+r][w] = qp[r]; }
    }
    __syncthreads();
    if (t < 16) {
        T[(size_t)b*HW + r0 + t]   = tred[t][0]+tred[t][1]+tred[t][2]+tred[t][3] + bthr[0];
        sqn[(size_t)b*HW + r0 + t] = qred[t][0]+qred[t][1]+qred[t][2]+qred[t][3];
    }
}

// ---------------------------------------------------------------------------
// K2: column sums D[j], swapped-MFMA, zero LDS, zero barriers.
// wave = 16 j x 1024 i. grid 1024 x 256 (4 waves). shfl-reduce + atomicAdd.
// ---------------------------------------------------------------------------
__global__ __launch_bounds__(256) void k_colsum(const short* __restrict__ emb,
    const float* __restrict__ sqn, const float* __restrict__ T,
    float* __restrict__ D)
{
    const int bid = ((blockIdx.x & 7) << 7) | (blockIdx.x >> 3);
    const int t = threadIdx.x, w = t >> 6, lane = t & 63, g = lane >> 4, n16 = lane & 15;
    const int wid = bid*4 + w;
    const int b = wid >> 10;
    const int jg = (wid & 1023) >> 2;
    const int isp = wid & 3;
    const size_t bbase = (size_t)b*HW;
    const size_t jbase = bbase + (size_t)jg*16;
    const short* ejp = emb + (jbase + n16)*FC + g*8;
    const short8 aj0 = *(const short8*)(ejp);
    const short8 aj1 = *(const short8*)(ejp + 32);
    const f32x4 sq4 = *(const f32x4*)(sqn + jbase + g*4);
    const f32x4 tj4 = *(const f32x4*)(T + jbase + g*4);
    f32x4 sqL, tjL;
    #pragma unroll
    for (int r = 0; r < 4; ++r) { sqL[r] = -L2E*sq4[r]; tjL[r] = -L2E*tj4[r]; }
    f32x4 csum = {0.f,0.f,0.f,0.f};
    const size_t ib0 = bbase + (size_t)isp*1024;
    const short* eip = emb + (ib0 + n16)*FC + g*8;
    short8 e0 = *(const short8*)(eip);
    short8 e1 = *(const short8*)(eip + 32);
    float sni = sqn[ib0 + n16];
    for (int it = 0; it < 64; ++it) {
        const short8 c0 = e0, c1 = e1;
        const float sn = sni;
        if (it < 63) {
            const short* p = emb + (ib0 + (size_t)(it+1)*16 + n16)*FC + g*8;
            e0 = *(const short8*)(p);
            e1 = *(const short8*)(p + 32);
            sni = sqn[ib0 + (it+1)*16 + n16];
        }
        f32x4 dot = {0.f,0.f,0.f,0.f};
        dot = __builtin_amdgcn_mfma_f32_16x16x32_bf16(aj0, c0, dot, 0, 0, 0);
        dot = __builtin_amdgcn_mfma_f32_16x16x32_bf16(aj1, c1, dot, 0, 0, 0);
        const float snL = -L2E*sn;
        #pragma unroll
        for (int r = 0; r < 4; ++r) {
            float x1 = fminf(fmaf(dot[r], 2.f*L2E, snL + sqL[r]), 0.f);
            float a_ = fmaxf(fmaf(fexp2(x1), L2E, tjL[r]), 0.f);
            csum[r] += fexp2(a_);
        }
    }
    #pragma unroll
    for (int r = 0; r < 4; ++r) {
        #pragma unroll
        for (int off = 1; off <= 8; off <<= 1) csum[r] += __shfl_xor(csum[r], off);
    }
    if (n16 == 0) {
        #pragma unroll
        for (int r = 0; r < 4; ++r) atomicAdd(&D[jbase + g*4 + r], csum[r]);
    }
}

// ---------------------------------------------------------------------------
// K3: fused score + normalize + PV, ZERO-barrier main loop.
// grid 256 x 256 (4 waves). wave jq: 64 i-rows x j-quarter of every tile.
// Swapped score mfma(ej, ei): lane holds P[j=g*4+r][i=n16] == exactly the
// A-fragment of mfma_16x16x16 PV. P never leaves registers.
// Cross-wave partial-acc reduction via 64KB LDS at the end (8 barriers total).
// ---------------------------------------------------------------------------
#define JT_STEP(K, bfC, bfN, ajC0, ajC1, ajN0, ajN1, sqC, tjC, dC, sqN, tjN, dN)  \
  {                                                                               \
    const int kn_ = (K) + 1 < 64 ? (K) + 1 : 63;                                  \
    { const short* sb_ = sct3 + (((size_t)(b*64 + kn_)*4 + jq)*16)*256 + lane*4;  \
      _Pragma("unroll")                                                           \
      for (int nn = 0; nn < 16; ++nn) bfN[nn] = *(const s16x4*)(sb_ + nn*256); }  \
    { const short* eb_ = emb + (bbase + (size_t)kn_*64 + jq*16 + n16)*FC + g*8;   \
      ajN0 = *(const short8*)(eb_); ajN1 = *(const short8*)(eb_ + 32); }          \
    { const size_t jb_ = bbase + (size_t)kn_*64 + jq*16 + g*4;                    \
      sqN = *(const f32x4*)(sqn + jb_); tjN = *(const f32x4*)(T + jb_);           \
      dN = *(const f32x4*)(D + jb_); }                                            \
    f32x4 sqL, tjL, idv;                                                          \
    _Pragma("unroll")                                                             \
    for (int r = 0; r < 4; ++r) {                                                 \
      sqL[r] = -L2E*sqC[r]; tjL[r] = -L2E*tjC[r]; idv[r] = frcp(dC[r]);           \
    }                                                                             \
    _Pragma("unroll")                                                             \
    for (int ic = 0; ic < 4; ++ic) {                                              \
      f32x4 dot = {0.f,0.f,0.f,0.f};                                              \
      dot = __builtin_amdgcn_mfma_f32_16x16x32_bf16(ajC0, eiB0[ic], dot, 0,0,0);  \
      dot = __builtin_amdgcn_mfma_f32_16x16x32_bf16(ajC1, eiB1[ic], dot, 0,0,0);  \
      s16x4 pk;                                                                   \
      _Pragma("unroll")                                                           \
      for (int r = 0; r < 4; ++r) {                                               \
        float x1 = fminf(fmaf(dot[r], 2.f*L2E, sniv[ic] + sqL[r]), 0.f);          \
        float a_ = fmaxf(fmaf(fexp2(x1), L2E, tjL[r]), 0.f);                      \
        pk[r] = f2bf(fexp2(a_) * idv[r]);                                         \
      }                                                                           \
      _Pragma("unroll")                                                           \
      for (int nn = 0; nn < 16; ++nn)                                             \
        acc2[ic][nn] = mfma16(pk, bfC[nn], acc2[ic][nn]);                         \
    }                                                                             \
  }

__global__ __launch_bounds__(256, 1) void k_attn(const float* __restrict__ fm,
    const short* __restrict__ emb, const float* __restrict__ sqn,
    const float* __restrict__ T, const float* __restrict__ D,
    const short* __restrict__ sct3, float* __restrict__ out)
{
    const int bid = ((blockIdx.x & 7) << 5) | (blockIdx.x >> 3);  // 256 blocks
    const int b = bid >> 6;
    const int i0 = (bid & 63) * 64;
    const int t = threadIdx.x, w = t >> 6, lane = t & 63, g = lane >> 4, n16 = lane & 15;
    const int jq = w;
    const size_t bbase = (size_t)b * HW;
    const size_t ibase = bbase + i0;
    __shared__ f32x4 part[4][256][4];   // 64 KB, epilogue reduction only

    // hoisted: ei B-fragments (4 i-tiles) + row-norm terms
    short8 eiB0[4], eiB1[4];
    f32x4 sniv;
    #pragma unroll
    for (int ic = 0; ic < 4; ++ic) {
        const short* p = emb + (ibase + ic*16 + n16)*FC + g*8;
        eiB0[ic] = *(const short8*)(p);
        eiB1[ic] = *(const short8*)(p + 32);
        sniv[ic] = -L2E * sqn[ibase + ic*16 + n16];
    }

    // prologue: tile-0 operands into the A set
    short8 ajA0, ajA1, ajB0, ajB1;
    {
        const short* eb = emb + (bbase + jq*16 + n16)*FC + g*8;
        ajA0 = *(const short8*)(eb); ajA1 = *(const short8*)(eb + 32);
    }
    f32x4 sqA, tjA, dA, sqB, tjB, dB;
    {
        const size_t jb = bbase + jq*16 + g*4;
        sqA = *(const f32x4*)(sqn + jb); tjA = *(const f32x4*)(T + jb);
        dA = *(const f32x4*)(D + jb);
    }
    s16x4 bfA[16], bfB[16];
    {
        const short* sb = sct3 + (((size_t)(b*64)*4 + jq)*16)*256 + lane*4;
        #pragma unroll
        for (int nn = 0; nn < 16; ++nn) bfA[nn] = *(const s16x4*)(sb + nn*256);
    }
    f32x4 acc2[4][16];
    #pragma unroll
    for (int ic = 0; ic < 4; ++ic)
        #pragma unroll
        for (int nn = 0; nn < 16; ++nn) acc2[ic][nn] = (f32x4){0.f,0.f,0.f,0.f};

    for (int k2 = 0; k2 < 64; k2 += 2) {
        JT_STEP(k2,   bfA, bfB, ajA0, ajA1, ajB0, ajB1, sqA, tjA, dA, sqB, tjB, dB);
        JT_STEP(k2+1, bfB, bfA, ajB0, ajB1, ajA0, ajA1, sqB, tjB, dB, sqA, tjA, dA);
    }

    // epilogue: 4-way cross-wave reduction, 16 rows (one ic) at a time
    #pragma unroll
    for (int ic = 0; ic < 4; ++ic) {
        if (ic) __syncthreads();
        #pragma unroll
        for (int nn = 0; nn < 16; ++nn) part[w][nn*16 + n16][g] = acc2[ic][nn];
        __syncthreads();
        #pragma unroll
        for (int k = 0; k < 4; ++k) {
            const int u = k*256 + t;
            const int ch = u >> 2, gg = u & 3;
            f32x4 s = part[0][ch][gg];
            s += part[1][ch][gg];
            s += part[2][ch][gg];
            s += part[3][ch][gg];
            #pragma unroll
            for (int r = 0; r < 4; ++r) {
                const size_t idx = (ibase + ic*16 + gg*4 + r)*CC + ch;
                out[idx] = fm[idx] + s[r];
            }
        }
    }
}

extern "C" void kernel_launch(void* const* d_in, const int* in_sizes, int n_in,
                              void* d_out, int out_size, void* d_ws, size_t ws_size,
                              hipStream_t stream)
{
    const float* fm   = (const float*)d_in[0];
    const float* Wemb = (const float*)d_in[1];
    const float* bemb = (const float*)d_in[2];
    const float* Watt = (const float*)d_in[3];
    const float* batt = (const float*)d_in[4];
    const float* Wthr = (const float*)d_in[5];
    const float* bthr = (const float*)d_in[6];
    char* ws = (char*)d_ws;
    short* emb   = (short*)(ws + OFF_EMB);
    short* sct3  = (short*)(ws + OFF_SCT3);
    float* sqn   = (float*)(ws + OFF_SQN);
    float* T     = (float*)(ws + OFF_T);
    float* D     = (float*)(ws + OFF_D);
    short* Wemb2 = (short*)(ws + OFF_WEMB2);
    short* Watt2 = (short*)(ws + OFF_WATT2);
    float* out = (float*)d_out;

    k_prep  <<<320,  256, 0, stream>>>(Wemb, Watt, Wemb2, Watt2, D);
    k_front <<<1024, 256, 0, stream>>>(fm, Wemb2, Watt2, bemb, batt, Wthr, bthr,
                                       emb, sct3, sqn, T);
    k_colsum<<<1024, 256, 0, stream>>>(emb, sqn, T, D);
    k_attn  <<<256,  256, 0, stream>>>(fm, emb, sqn, T, D, sct3, out);
}

// Round 7
// 111.227 us; speedup vs baseline: 1.6357x; 1.6357x over previous
//
#include <hip/hip_runtime.h>
#include <hip/hip_bf16.h>
#include <math.h>

typedef __attribute__((ext_vector_type(8))) short short8;
typedef __attribute__((ext_vector_type(4))) short s16x4;
typedef __attribute__((ext_vector_type(4))) float f32x4;

#define BB 4
#define HW 4096
#define CC 256
#define FC 64
#define L2E 1.4426950408889634f

// ws byte offsets
#define OFF_EMB   0                      // short[16384*64]   = 2 MB
#define OFF_SCT2  (2*1024*1024)          // short[4*64*8*256*8] = 8 MB
#define OFF_SQN   (OFF_SCT2 + 8*1024*1024)
#define OFF_T     (OFF_SQN + 65536)
#define OFF_D     (OFF_T   + 65536)
#define OFF_WEMB2 (OFF_D   + 65536)      // short[32*64*8] = 32 KB
#define OFF_WATT2 (OFF_WEMB2 + 32768)    // short[32*256*8] = 128 KB

static __device__ __forceinline__ short f2bf(float f) {
    __hip_bfloat16 h = __float2bfloat16(f);
    return *reinterpret_cast<short*>(&h);
}
static __device__ __forceinline__ float bf2f(short s) {
    __hip_bfloat16 h = *reinterpret_cast<__hip_bfloat16*>(&s);
    return __bfloat162float(h);
}
static __device__ __forceinline__ float fexp2(float x) {
#if __has_builtin(__builtin_amdgcn_exp2f)
    return __builtin_amdgcn_exp2f(x);
#else
    float r; asm("v_exp_f32 %0, %1" : "=v"(r) : "v"(x)); return r;
#endif
}
static __device__ __forceinline__ float frcp(float x) {
#if __has_builtin(__builtin_amdgcn_rcpf)
    return __builtin_amdgcn_rcpf(x);
#else
    return 1.0f / x;
#endif
}
// transform: sim=exp(-relu(d2)), A=relu(sim-T), P=exp(A)/D  (exp2-folded)
static __device__ __forceinline__ short xf1(float dot, float sq, float tt,
                                            float id, float sni) {
    float x1 = fminf(fmaf(dot, 2.f*L2E, fmaf(-L2E, sq, sni)), 0.f);
    float e1 = fexp2(x1);
    float a_ = fmaxf(fmaf(e1, L2E, -L2E*tt), 0.f);
    return f2bf(fexp2(a_) * id);
}

// ---------------------------------------------------------------------------
// K0: weight conversion to tiled bf16 B-fragment layouts + D zero.
// ---------------------------------------------------------------------------
__global__ __launch_bounds__(256) void k_prep(const float* __restrict__ Wemb,
    const float* __restrict__ Watt, short* __restrict__ Wemb2,
    short* __restrict__ Watt2, float* __restrict__ D)
{
    const int bid = blockIdx.x, t = threadIdx.x;
    if (bid < 256) {
        Watt2[(size_t)(t>>3)*2048 + bid*8 + (t&7)] = f2bf(Watt[(size_t)bid*256 + t]);
        if (bid < 64) D[bid*256 + t] = 0.f;
    } else {
        const int f = bid - 256;
        Wemb2[(size_t)(t>>3)*512 + f*8 + (t&7)] = f2bf(Wemb[(size_t)f*256 + t]);
    }
}

// ---------------------------------------------------------------------------
// K1 (fused emb + shortcut + threshold, all MFMA). grid 1024 x 256.
// ---------------------------------------------------------------------------
__global__ __launch_bounds__(256) void k_front(const float* __restrict__ fm,
    const short* __restrict__ Wemb2, const short* __restrict__ Watt2,
    const float* __restrict__ bemb, const float* __restrict__ batt,
    const float* __restrict__ wthr, const float* __restrict__ bthr,
    short* __restrict__ emb, short* __restrict__ sct2,
    float* __restrict__ sqn, float* __restrict__ T)
{
    const int blk = blockIdx.x;
    const int b = blk >> 8;
    const int r0 = (blk & 255) * 16;
    const int t = threadIdx.x;
    const int w = t >> 6, lane = t & 63, g = lane >> 4, n16 = lane & 15;
    __shared__ short fmt[16*256];
    __shared__ float tred[16][4];
    __shared__ float qred[16][4];
    #pragma unroll
    for (int v = t; v < 512; v += 256) {
        const int row = v >> 5, c32 = v & 31;
        const float4* src = (const float4*)(fm + ((size_t)b*HW + r0 + row)*CC + c32*8);
        float4 x0 = src[0], x1 = src[1];
        short8 pv;
        pv[0]=f2bf(x0.x); pv[1]=f2bf(x0.y); pv[2]=f2bf(x0.z); pv[3]=f2bf(x0.w);
        pv[4]=f2bf(x1.x); pv[5]=f2bf(x1.y); pv[6]=f2bf(x1.z); pv[7]=f2bf(x1.w);
        *(short8*)((char*)fmt + row*512 + ((c32*16) ^ ((row&7)<<4))) = pv;
    }
    __syncthreads();
    const int cb = w*64, fb = w*16;
    f32x4 acc[4], acce;
    #pragma unroll
    for (int nn = 0; nn < 4; ++nn) acc[nn] = (f32x4){0.f,0.f,0.f,0.f};
    acce = (f32x4){0.f,0.f,0.f,0.f};
    #pragma unroll
    for (int kk = 0; kk < 8; ++kk) {
        const int kc = kk*4 + g;
        short8 a = *(const short8*)((const char*)fmt + n16*512 + ((kc*16) ^ ((n16&7)<<4)));
        const short* wb = Watt2 + (size_t)kc*2048 + (cb + n16)*8;
        #pragma unroll
        for (int nn = 0; nn < 4; ++nn) {
            short8 bv = *(const short8*)(wb + nn*128);
            acc[nn] = __builtin_amdgcn_mfma_f32_16x16x32_bf16(a, bv, acc[nn], 0, 0, 0);
        }
        short8 be = *(const short8*)(Wemb2 + (size_t)kc*512 + (fb + n16)*8);
        acce = __builtin_amdgcn_mfma_f32_16x16x32_bf16(a, be, acce, 0, 0, 0);
    }
    float tp[4] = {0.f,0.f,0.f,0.f};
    const int jt_ = r0 >> 6;
    const int jc0 = (r0 & 63) >> 3;
    const size_t tilebase = ((size_t)b*64 + jt_)*8;
    #pragma unroll
    for (int nn = 0; nn < 4; ++nn) {
        const int ch = cb + nn*16 + n16;
        const float ba_ = batt[ch], wt_ = wthr[ch];
        float v[4];
        #pragma unroll
        for (int r = 0; r < 4; ++r) { v[r] = acc[nn][r] + ba_; tp[r] = fmaf(v[r], wt_, tp[r]); }
        const int jc = jc0 + (g >> 1);
        const int jw0 = (g & 1)*4;
        short* dstp = sct2 + (tilebase + jc)*2048 + (size_t)ch*8;
        unsigned u01 = (unsigned short)f2bf(v[0]) | ((unsigned)(unsigned short)f2bf(v[1]) << 16);
        unsigned u23 = (unsigned short)f2bf(v[2]) | ((unsigned)(unsigned short)f2bf(v[3]) << 16);
        *(unsigned*)(dstp + jw0)     = u01;
        *(unsigned*)(dstp + jw0 + 2) = u23;
    }
    #pragma unroll
    for (int r = 0; r < 4; ++r)
        #pragma unroll
        for (int off = 1; off <= 8; off <<= 1) tp[r] += __shfl_xor(tp[r], off);
    const int f = fb + n16;
    const float be_ = bemb[f];
    float qp[4];
    #pragma unroll
    for (int r = 0; r < 4; ++r) {
        short bv = f2bf(acce[r] + be_);
        emb[((size_t)b*HW + r0 + g*4 + r)*FC + f] = bv;
        float ef = bf2f(bv);
        qp[r] = ef*ef;
        #pragma unroll
        for (int off = 1; off <= 8; off <<= 1) qp[r] += __shfl_xor(qp[r], off);
    }
    if (n16 == 0) {
        #pragma unroll
        for (int r = 0; r < 4; ++r) { tred[g*4+r][w] = tp[r]; qred[g*4+r][w] = qp[r]; }
    }
    __syncthreads();
    if (t < 16) {
        T[(size_t)b*HW + r0 + t]   = tred[t][0]+tred[t][1]+tred[t][2]+tred[t][3] + bthr[0];
        sqn[(size_t)b*HW + r0 + t] = qred[t][0]+qred[t][1]+qred[t][2]+qred[t][3];
    }
}

// ---------------------------------------------------------------------------
// K2: column sums D[j]. grid 2048 x 256. 1 barrier/iter, dbuf ei.
// ---------------------------------------------------------------------------
__global__ __launch_bounds__(256) void k_colsum(const short* __restrict__ emb,
    const float* __restrict__ sqn, const float* __restrict__ T,
    float* __restrict__ D)
{
    const int bid = blockIdx.x;
    const int split = bid & 7, jt = (bid >> 3) & 63, b = bid >> 9;
    const int t = threadIdx.x, w = t >> 6, lane = t & 63, g = lane >> 4, n16 = lane & 15;
    const size_t jbase = (size_t)b*HW + jt*64;
    __shared__ short ej[64*64];
    __shared__ short ei[2][64*64];
    __shared__ float sqni[2][64];
    #pragma unroll
    for (int v = t; v < 512; v += 256) {
        const int row = v >> 3, c8 = v & 7;
        short8 x = *(const short8*)(emb + (jbase + row)*FC + c8*8);
        *(short8*)((char*)ej + row*128 + ((c8*16) ^ ((row&7)<<4))) = x;
    }
    const int jl = w*16 + n16;
    const float sqjL = -L2E * sqn[jbase + jl];
    const float tjL  = -L2E * T[jbase + jl];
    const int srow0 = t >> 3, srow1 = (t >> 3) + 32, sc8 = t & 7;
    const int sb0 = srow0*128 + ((sc8*16) ^ ((srow0&7)<<4));
    const int sb1 = srow1*128 + ((sc8*16) ^ ((srow1&7)<<4));
    const size_t base0 = (size_t)b*HW + (size_t)split*512;
    short8 stg0 = *(const short8*)(emb + (base0 + srow0)*FC + sc8*8);
    short8 stg1 = *(const short8*)(emb + (base0 + srow1)*FC + sc8*8);
    float stgq = (t < 64) ? sqn[base0 + t] : 0.f;
    *(short8*)((char*)ei[0] + sb0) = stg0;
    *(short8*)((char*)ei[0] + sb1) = stg1;
    if (t < 64) sqni[0][t] = stgq;
    stg0 = *(const short8*)(emb + (base0 + 64 + srow0)*FC + sc8*8);
    stg1 = *(const short8*)(emb + (base0 + 64 + srow1)*FC + sc8*8);
    stgq = (t < 64) ? sqn[base0 + 64 + t] : 0.f;
    __syncthreads();
    const short8 bf0 = *(const short8*)((const char*)ej + jl*128 + ((g*16)     ^ ((jl&7)<<4)));
    const short8 bf1 = *(const short8*)((const char*)ej + jl*128 + (((g+4)*16) ^ ((jl&7)<<4)));
    float csum = 0.f;
    for (int it = 0; it < 8; ++it) {
        if (it < 7) {
            char* eib = (char*)ei[(it+1)&1];
            *(short8*)(eib + sb0) = stg0;
            *(short8*)(eib + sb1) = stg1;
            if (t < 64) sqni[(it+1)&1][t] = stgq;
            if (it < 6) {
                const size_t nb = base0 + (size_t)(it+2)*64;
                stg0 = *(const short8*)(emb + (nb + srow0)*FC + sc8*8);
                stg1 = *(const short8*)(emb + (nb + srow1)*FC + sc8*8);
                stgq = (t < 64) ? sqn[nb + t] : 0.f;
            }
        }
        const char* eib = (const char*)ei[it&1];
        const float* sqc = sqni[it&1];
        #pragma unroll
        for (int m = 0; m < 4; ++m) {
            const int arow = m*16 + n16;
            short8 a0 = *(const short8*)(eib + arow*128 + ((g*16)     ^ ((arow&7)<<4)));
            short8 a1 = *(const short8*)(eib + arow*128 + (((g+4)*16) ^ ((arow&7)<<4)));
            f32x4 dot = {0.f,0.f,0.f,0.f};
            dot = __builtin_amdgcn_mfma_f32_16x16x32_bf16(a0, bf0, dot, 0, 0, 0);
            dot = __builtin_amdgcn_mfma_f32_16x16x32_bf16(a1, bf1, dot, 0, 0, 0);
            #pragma unroll
            for (int r = 0; r < 4; ++r) {
                float x1 = fminf(fmaf(dot[r], 2.f*L2E, fmaf(-L2E, sqc[m*16 + g*4 + r], sqjL)), 0.f);
                float e1 = fexp2(x1);
                float a_ = fmaxf(fmaf(e1, L2E, tjL), 0.f);
                csum += fexp2(a_);
            }
        }
        __syncthreads();
    }
    csum += __shfl_xor(csum, 16);
    csum += __shfl_xor(csum, 32);
    if (lane < 16) atomicAdd(&D[jbase + jl], csum);
}

// ---------------------------------------------------------------------------
// K3: fused score + normalize + PV.  grid 512 x 256 (4 waves), 32 rows/block,
// 2 blocks/CU (independent barrier groups fill each other's stalls).
// wave w: score j-quarter w (cols w*16..+15, all 32 rows);
//         PV channels w*64..+63 (all 32 rows).
// 1 barrier/jt; dbuf ej + P; B-frags/scalars/staging prefetched 1 jt ahead.
// ---------------------------------------------------------------------------
#define ATTN_ITER(K, bfC, sqC, tC, dC, bfN, sqN, tN, dN)                         \
  {                                                                              \
    const int kn = (K) < 63 ? (K) + 1 : 63;                                      \
    const size_t jbn = bbase + (size_t)kn * 64;                                  \
    sqN = sqn[jbn + jl]; tN = T[jbn + jl]; dN = D[jbn + jl];                     \
    {                                                                            \
      const short* sbn = sct2 + ((size_t)(b*64 + kn)*8)*2048 + (size_t)(w*64 + n16)*8; \
      _Pragma("unroll")                                                          \
      for (int nn = 0; nn < 4; ++nn) {                                           \
        _Pragma("unroll")                                                        \
        for (int kc = 0; kc < 2; ++kc)                                           \
          bfN[nn*2+kc] = *(const short8*)(sbn + (size_t)(kc*4+g)*2048 + nn*128); \
      }                                                                          \
    }                                                                            \
    {                                                                            \
      const float iD   = frcp(dC);                                               \
      const float sqjL = -L2E * sqC;                                             \
      const float tjL  = -L2E * tC;                                              \
      const char* ejb = (const char*)ejlds[(K)&1];                               \
      char* Pb = (char*)Plds[(K)&1];                                             \
      short8 b0 = *(const short8*)(ejb + jl*128 + ((g*16)     ^ ((jl&7)<<4)));   \
      short8 b1 = *(const short8*)(ejb + jl*128 + (((g+4)*16) ^ ((jl&7)<<4)));   \
      _Pragma("unroll")                                                          \
      for (int t2 = 0; t2 < 2; ++t2) {                                           \
        f32x4 dot = {0.f,0.f,0.f,0.f};                                           \
        dot = __builtin_amdgcn_mfma_f32_16x16x32_bf16(aQ0[t2], b0, dot, 0,0,0);  \
        dot = __builtin_amdgcn_mfma_f32_16x16x32_bf16(aQ1[t2], b1, dot, 0,0,0);  \
        _Pragma("unroll")                                                        \
        for (int r = 0; r < 4; ++r) {                                            \
          float x1 = fminf(fmaf(dot[r], 2.f*L2E, snL[t2][r] + sqjL), 0.f);       \
          float e1 = fexp2(x1);                                                  \
          float a_ = fmaxf(fmaf(e1, L2E, tjL), 0.f);                             \
          float p  = fexp2(a_) * iD;                                             \
          const int prow = t2*16 + g*4 + r;                                      \
          *(short*)(Pb + prow*128 + (((jl>>3) ^ (prow&7))<<4) + (jl&7)*2) = f2bf(p); \
        }                                                                        \
      }                                                                          \
    }                                                                            \
    if ((K) < 63) {                                                              \
      *(short8*)((char*)ejlds[((K)+1)&1] + sbyte0) = stg0;                       \
      *(short8*)((char*)ejlds[((K)+1)&1] + sbyte1) = stg1;                       \
      const int k2n = (K) < 62 ? (K) + 2 : 63;                                   \
      stg0 = *(const short8*)(emb + (bbase + (size_t)k2n*64 + srow0)*FC + sc8*8); \
      stg1 = *(const short8*)(emb + (bbase + (size_t)k2n*64 + srow1)*FC + sc8*8); \
    }                                                                            \
    __syncthreads();                                                             \
    {                                                                            \
      const char* Pb = (const char*)Plds[(K)&1];                                 \
      _Pragma("unroll")                                                          \
      for (int m = 0; m < 2; ++m) {                                              \
        const int prow = m*16 + n16;                                             \
        short8 pa0 = *(const short8*)(Pb + prow*128 + (((0*4+g)<<4) ^ ((prow&7)<<4))); \
        short8 pa1 = *(const short8*)(Pb + prow*128 + (((1*4+g)<<4) ^ ((prow&7)<<4))); \
        _Pragma("unroll")                                                        \
        for (int nn = 0; nn < 4; ++nn) {                                         \
          acc[m][nn] = __builtin_amdgcn_mfma_f32_16x16x32_bf16(pa0, bfC[nn*2+0], acc[m][nn], 0,0,0); \
          acc[m][nn] = __builtin_amdgcn_mfma_f32_16x16x32_bf16(pa1, bfC[nn*2+1], acc[m][nn], 0,0,0); \
        }                                                                        \
      }                                                                          \
    }                                                                            \
  }

__global__ __launch_bounds__(256, 2) void k_attn(const float* __restrict__ fm,
    const short* __restrict__ emb, const float* __restrict__ sqn,
    const float* __restrict__ T, const float* __restrict__ D,
    const short* __restrict__ sct2, float* __restrict__ out)
{
    const int bid = ((blockIdx.x & 7) << 6) | (blockIdx.x >> 3);  // 512 blocks
    const int b = bid >> 7;
    const int i0 = (bid & 127) * 32;
    const int t = threadIdx.x, w = t >> 6, lane = t & 63, g = lane >> 4, n16 = lane & 15;
    const size_t bbase = (size_t)b * HW;
    const size_t ibase = bbase + i0;
    __shared__ short ejlds[2][64*64];   // 16 KB
    __shared__ short Plds[2][32*64];    //  8 KB

    const int jl = w*16 + n16;

    // ei fragments (MFMA B-operand for score) + per-row norm terms
    short8 aQ0[2], aQ1[2];
    float snL[2][4];
    #pragma unroll
    for (int t2 = 0; t2 < 2; ++t2) {
        const size_t qr = ibase + t2*16 + n16;
        aQ0[t2] = *(const short8*)(emb + qr*FC + g*8);
        aQ1[t2] = *(const short8*)(emb + qr*FC + 32 + g*8);
        #pragma unroll
        for (int r = 0; r < 4; ++r)
            snL[t2][r] = -L2E * sqn[ibase + t2*16 + g*4 + r];
    }
    const int srow0 = t >> 3, srow1 = (t >> 3) + 32, sc8 = t & 7;
    const int sbyte0 = srow0*128 + ((sc8*16) ^ ((srow0&7)<<4));
    const int sbyte1 = srow1*128 + ((sc8*16) ^ ((srow1&7)<<4));
    short8 stg0 = *(const short8*)(emb + (bbase + srow0)*FC + sc8*8);
    short8 stg1 = *(const short8*)(emb + (bbase + srow1)*FC + sc8*8);
    *(short8*)((char*)ejlds[0] + sbyte0) = stg0;
    *(short8*)((char*)ejlds[0] + sbyte1) = stg1;
    stg0 = *(const short8*)(emb + (bbase + 64 + srow0)*FC + sc8*8);
    stg1 = *(const short8*)(emb + (bbase + 64 + srow1)*FC + sc8*8);

    // prologue scalars: tile0 (consumed in prologue) + tile1 (window 0)
    const float sq0 = sqn[bbase + jl], t0q = T[bbase + jl], d0q = D[bbase + jl];
    float sqA, tA, dA, sqB, tB, dB;
    sqA = sqn[bbase + 64 + jl]; tA = T[bbase + 64 + jl]; dA = D[bbase + 64 + jl];
    short8 bfA[8], bfB[8];
    {
        const short* sb0 = sct2 + ((size_t)(b*64)*8)*2048 + (size_t)(w*64 + n16)*8;
        #pragma unroll
        for (int nn = 0; nn < 4; ++nn)
            #pragma unroll
            for (int kc = 0; kc < 2; ++kc)
                bfA[nn*2+kc] = *(const short8*)(sb0 + (size_t)(kc*4+g)*2048 + nn*128);
    }
    f32x4 acc[2][4];
    #pragma unroll
    for (int m = 0; m < 2; ++m)
        #pragma unroll
        for (int nn = 0; nn < 4; ++nn) acc[m][nn] = (f32x4){0.f,0.f,0.f,0.f};
    __syncthreads();            // ej[0] visible

    // prologue window: score tile 0 -> P[0]; stage ej[1]
    {
        const char* ejb = (const char*)ejlds[0];
        char* Pb = (char*)Plds[0];
        const float iD = frcp(d0q);
        const float sqjL = -L2E * sq0;
        const float tjL  = -L2E * t0q;
        short8 b0 = *(const short8*)(ejb + jl*128 + ((g*16)     ^ ((jl&7)<<4)));
        short8 b1 = *(const short8*)(ejb + jl*128 + (((g+4)*16) ^ ((jl&7)<<4)));
        #pragma unroll
        for (int t2 = 0; t2 < 2; ++t2) {
            f32x4 dot = {0.f,0.f,0.f,0.f};
            dot = __builtin_amdgcn_mfma_f32_16x16x32_bf16(aQ0[t2], b0, dot, 0,0,0);
            dot = __builtin_amdgcn_mfma_f32_16x16x32_bf16(aQ1[t2], b1, dot, 0,0,0);
            #pragma unroll
            for (int r = 0; r < 4; ++r) {
                float x1 = fminf(fmaf(dot[r], 2.f*L2E, snL[t2][r] + sqjL), 0.f);
                float e1 = fexp2(x1);
                float a_ = fmaxf(fmaf(e1, L2E, tjL), 0.f);
                float p  = fexp2(a_) * iD;
                const int prow = t2*16 + g*4 + r;
                *(short*)(Pb + prow*128 + (((jl>>3) ^ (prow&7))<<4) + (jl&7)*2) = f2bf(p);
            }
        }
        *(short8*)((char*)ejlds[1] + sbyte0) = stg0;
        *(short8*)((char*)ejlds[1] + sbyte1) = stg1;
        stg0 = *(const short8*)(emb + (bbase + 128 + srow0)*FC + sc8*8);
        stg1 = *(const short8*)(emb + (bbase + 128 + srow1)*FC + sc8*8);
        __syncthreads();        // P[0], ej[1] visible
    }

    for (int k2 = 0; k2 < 62; k2 += 2) {
        ATTN_ITER(k2,   bfA, sqA, tA, dA, bfB, sqB, tB, dB);
        ATTN_ITER(k2+1, bfB, sqB, tB, dB, bfA, sqA, tA, dA);
    }
    ATTN_ITER(62, bfA, sqA, tA, dA, bfB, sqB, tB, dB);

    // epilogue: PV tile 63 (P[1], bfB)
    {
        const char* Pb = (const char*)Plds[1];
        #pragma unroll
        for (int m = 0; m < 2; ++m) {
            const int prow = m*16 + n16;
            short8 pa0 = *(const short8*)(Pb + prow*128 + (((0*4+g)<<4) ^ ((prow&7)<<4)));
            short8 pa1 = *(const short8*)(Pb + prow*128 + (((1*4+g)<<4) ^ ((prow&7)<<4)));
            #pragma unroll
            for (int nn = 0; nn < 4; ++nn) {
                acc[m][nn] = __builtin_amdgcn_mfma_f32_16x16x32_bf16(pa0, bfB[nn*2+0], acc[m][nn], 0,0,0);
                acc[m][nn] = __builtin_amdgcn_mfma_f32_16x16x32_bf16(pa1, bfB[nn*2+1], acc[m][nn], 0,0,0);
            }
        }
    }

    #pragma unroll
    for (int m = 0; m < 2; ++m)
        #pragma unroll
        for (int r = 0; r < 4; ++r) {
            const size_t row = ibase + m*16 + g*4 + r;
            #pragma unroll
            for (int nn = 0; nn < 4; ++nn) {
                const size_t idx = row*CC + w*64 + nn*16 + n16;
                out[idx] = fm[idx] + acc[m][nn][r];
            }
        }
}

extern "C" void kernel_launch(void* const* d_in, const int* in_sizes, int n_in,
                              void* d_out, int out_size, void* d_ws, size_t ws_size,
                              hipStream_t stream)
{
    const float* fm   = (const float*)d_in[0];
    const float* Wemb = (const float*)d_in[1];
    const float* bemb = (const float*)d_in[2];
    const float* Watt = (const float*)d_in[3];
    const float* batt = (const float*)d_in[4];
    const float* Wthr = (const float*)d_in[5];
    const float* bthr = (const float*)d_in[6];
    char* ws = (char*)d_ws;
    short* emb   = (short*)(ws + OFF_EMB);
    short* sct2  = (short*)(ws + OFF_SCT2);
    float* sqn   = (float*)(ws + OFF_SQN);
    float* T     = (float*)(ws + OFF_T);
    float* D     = (float*)(ws + OFF_D);
    short* Wemb2 = (short*)(ws + OFF_WEMB2);
    short* Watt2 = (short*)(ws + OFF_WATT2);
    float* out = (float*)d_out;

    k_prep  <<<320,  256, 0, stream>>>(Wemb, Watt, Wemb2, Watt2, D);
    k_front <<<1024, 256, 0, stream>>>(fm, Wemb2, Watt2, bemb, batt, Wthr, bthr,
                                       emb, sct2, sqn, T);
    k_colsum<<<2048, 256, 0, stream>>>(emb, sqn, T, D);
    k_attn  <<<512,  256, 0, stream>>>(fm, emb, sqn, T, D, sct2, out);
}

// Round 8
// 110.178 us; speedup vs baseline: 1.6513x; 1.0095x over previous
//
#include <hip/hip_runtime.h>
#include <hip/hip_bf16.h>
#include <math.h>

typedef __attribute__((ext_vector_type(8))) short short8;
typedef __attribute__((ext_vector_type(4))) float f32x4;

#define BB 4
#define HW 4096
#define CC 256
#define FC 64
#define L2E 1.4426950408889634f

// ws byte offsets
#define OFF_EMB   0                      // short[16384*64]   = 2 MB
#define OFF_SCT2  (2*1024*1024)          // short[4*64*8*256*8] = 8 MB
#define OFF_SQN   (OFF_SCT2 + 8*1024*1024)
#define OFF_T     (OFF_SQN + 65536)
#define OFF_D     (OFF_T   + 65536)
#define OFF_WEMB2 (OFF_D   + 65536)      // short[32*64*8] = 32 KB
#define OFF_WATT2 (OFF_WEMB2 + 32768)    // short[32*256*8] = 128 KB

static __device__ __forceinline__ short f2bf(float f) {
    __hip_bfloat16 h = __float2bfloat16(f);
    return *reinterpret_cast<short*>(&h);
}
static __device__ __forceinline__ float bf2f(short s) {
    __hip_bfloat16 h = *reinterpret_cast<__hip_bfloat16*>(&s);
    return __bfloat162float(h);
}
static __device__ __forceinline__ float fexp2(float x) {
#if __has_builtin(__builtin_amdgcn_exp2f)
    return __builtin_amdgcn_exp2f(x);
#else
    float r; asm("v_exp_f32 %0, %1" : "=v"(r) : "v"(x)); return r;
#endif
}
static __device__ __forceinline__ float frcp(float x) {
#if __has_builtin(__builtin_amdgcn_rcpf)
    return __builtin_amdgcn_rcpf(x);
#else
    return 1.0f / x;
#endif
}
#define MFMA32(a, b, c) __builtin_amdgcn_mfma_f32_16x16x32_bf16(a, b, c, 0, 0, 0)

// ---------------------------------------------------------------------------
// K0: weight conversion to tiled bf16 B-fragment layouts + D zero.
// ---------------------------------------------------------------------------
__global__ __launch_bounds__(256) void k_prep(const float* __restrict__ Wemb,
    const float* __restrict__ Watt, short* __restrict__ Wemb2,
    short* __restrict__ Watt2, float* __restrict__ D)
{
    const int bid = blockIdx.x, t = threadIdx.x;
    if (bid < 256) {
        Watt2[(size_t)(t>>3)*2048 + bid*8 + (t&7)] = f2bf(Watt[(size_t)bid*256 + t]);
        if (bid < 64) D[bid*256 + t] = 0.f;
    } else {
        const int f = bid - 256;
        Wemb2[(size_t)(t>>3)*512 + f*8 + (t&7)] = f2bf(Wemb[(size_t)f*256 + t]);
    }
}

// ---------------------------------------------------------------------------
// K1 (fused emb + shortcut + threshold, all MFMA). grid 1024 x 256.
// ---------------------------------------------------------------------------
__global__ __launch_bounds__(256) void k_front(const float* __restrict__ fm,
    const short* __restrict__ Wemb2, const short* __restrict__ Watt2,
    const float* __restrict__ bemb, const float* __restrict__ batt,
    const float* __restrict__ wthr, const float* __restrict__ bthr,
    short* __restrict__ emb, short* __restrict__ sct2,
    float* __restrict__ sqn, float* __restrict__ T)
{
    const int blk = blockIdx.x;
    const int b = blk >> 8;
    const int r0 = (blk & 255) * 16;
    const int t = threadIdx.x;
    const int w = t >> 6, lane = t & 63, g = lane >> 4, n16 = lane & 15;
    __shared__ short fmt[16*256];
    __shared__ float tred[16][4];
    __shared__ float qred[16][4];
    #pragma unroll
    for (int v = t; v < 512; v += 256) {
        const int row = v >> 5, c32 = v & 31;
        const float4* src = (const float4*)(fm + ((size_t)b*HW + r0 + row)*CC + c32*8);
        float4 x0 = src[0], x1 = src[1];
        short8 pv;
        pv[0]=f2bf(x0.x); pv[1]=f2bf(x0.y); pv[2]=f2bf(x0.z); pv[3]=f2bf(x0.w);
        pv[4]=f2bf(x1.x); pv[5]=f2bf(x1.y); pv[6]=f2bf(x1.z); pv[7]=f2bf(x1.w);
        *(short8*)((char*)fmt + row*512 + ((c32*16) ^ ((row&7)<<4))) = pv;
    }
    __syncthreads();
    const int cb = w*64, fb = w*16;
    f32x4 acc[4], acce;
    #pragma unroll
    for (int nn = 0; nn < 4; ++nn) acc[nn] = (f32x4){0.f,0.f,0.f,0.f};
    acce = (f32x4){0.f,0.f,0.f,0.f};
    #pragma unroll
    for (int kk = 0; kk < 8; ++kk) {
        const int kc = kk*4 + g;
        short8 a = *(const short8*)((const char*)fmt + n16*512 + ((kc*16) ^ ((n16&7)<<4)));
        const short* wb = Watt2 + (size_t)kc*2048 + (cb + n16)*8;
        #pragma unroll
        for (int nn = 0; nn < 4; ++nn) {
            short8 bv = *(const short8*)(wb + nn*128);
            acc[nn] = MFMA32(a, bv, acc[nn]);
        }
        short8 be = *(const short8*)(Wemb2 + (size_t)kc*512 + (fb + n16)*8);
        acce = MFMA32(a, be, acce);
    }
    float tp[4] = {0.f,0.f,0.f,0.f};
    const int jt_ = r0 >> 6;
    const int jc0 = (r0 & 63) >> 3;
    const size_t tilebase = ((size_t)b*64 + jt_)*8;
    #pragma unroll
    for (int nn = 0; nn < 4; ++nn) {
        const int ch = cb + nn*16 + n16;
        const float ba_ = batt[ch], wt_ = wthr[ch];
        float v[4];
        #pragma unroll
        for (int r = 0; r < 4; ++r) { v[r] = acc[nn][r] + ba_; tp[r] = fmaf(v[r], wt_, tp[r]); }
        const int jc = jc0 + (g >> 1);
        const int jw0 = (g & 1)*4;
        short* dstp = sct2 + (tilebase + jc)*2048 + (size_t)ch*8;
        unsigned u01 = (unsigned short)f2bf(v[0]) | ((unsigned)(unsigned short)f2bf(v[1]) << 16);
        unsigned u23 = (unsigned short)f2bf(v[2]) | ((unsigned)(unsigned short)f2bf(v[3]) << 16);
        *(unsigned*)(dstp + jw0)     = u01;
        *(unsigned*)(dstp + jw0 + 2) = u23;
    }
    #pragma unroll
    for (int r = 0; r < 4; ++r)
        #pragma unroll
        for (int off = 1; off <= 8; off <<= 1) tp[r] += __shfl_xor(tp[r], off);
    const int f = fb + n16;
    const float be_ = bemb[f];
    float qp[4];
    #pragma unroll
    for (int r = 0; r < 4; ++r) {
        short bv = f2bf(acce[r] + be_);
        emb[((size_t)b*HW + r0 + g*4 + r)*FC + f] = bv;
        float ef = bf2f(bv);
        qp[r] = ef*ef;
        #pragma unroll
        for (int off = 1; off <= 8; off <<= 1) qp[r] += __shfl_xor(qp[r], off);
    }
    if (n16 == 0) {
        #pragma unroll
        for (int r = 0; r < 4; ++r) { tred[g*4+r][w] = tp[r]; qred[g*4+r][w] = qp[r]; }
    }
    __syncthreads();
    if (t < 16) {
        T[(size_t)b*HW + r0 + t]   = tred[t][0]+tred[t][1]+tred[t][2]+tred[t][3] + bthr[0];
        sqn[(size_t)b*HW + r0 + t] = qred[t][0]+qred[t][1]+qred[t][2]+qred[t][3];
    }
}

// ---------------------------------------------------------------------------
// K2: column sums D[j]. grid 2048 x 256. 1 barrier/iter, dbuf ei.
// ---------------------------------------------------------------------------
__global__ __launch_bounds__(256) void k_colsum(const short* __restrict__ emb,
    const float* __restrict__ sqn, const float* __restrict__ T,
    float* __restrict__ D)
{
    const int bid = blockIdx.x;
    const int split = bid & 7, jt = (bid >> 3) & 63, b = bid >> 9;
    const int t = threadIdx.x, w = t >> 6, lane = t & 63, g = lane >> 4, n16 = lane & 15;
    const size_t jbase = (size_t)b*HW + jt*64;
    __shared__ short ej[64*64];
    __shared__ short ei[2][64*64];
    __shared__ float sqni[2][64];
    #pragma unroll
    for (int v = t; v < 512; v += 256) {
        const int row = v >> 3, c8 = v & 7;
        short8 x = *(const short8*)(emb + (jbase + row)*FC + c8*8);
        *(short8*)((char*)ej + row*128 + ((c8*16) ^ ((row&7)<<4))) = x;
    }
    const int jl = w*16 + n16;
    const float sqjL = -L2E * sqn[jbase + jl];
    const float tjL  = -L2E * T[jbase + jl];
    const int srow0 = t >> 3, srow1 = (t >> 3) + 32, sc8 = t & 7;
    const int sb0 = srow0*128 + ((sc8*16) ^ ((srow0&7)<<4));
    const int sb1 = srow1*128 + ((sc8*16) ^ ((srow1&7)<<4));
    const size_t base0 = (size_t)b*HW + (size_t)split*512;
    short8 stg0 = *(const short8*)(emb + (base0 + srow0)*FC + sc8*8);
    short8 stg1 = *(const short8*)(emb + (base0 + srow1)*FC + sc8*8);
    float stgq = (t < 64) ? sqn[base0 + t] : 0.f;
    *(short8*)((char*)ei[0] + sb0) = stg0;
    *(short8*)((char*)ei[0] + sb1) = stg1;
    if (t < 64) sqni[0][t] = stgq;
    stg0 = *(const short8*)(emb + (base0 + 64 + srow0)*FC + sc8*8);
    stg1 = *(const short8*)(emb + (base0 + 64 + srow1)*FC + sc8*8);
    stgq = (t < 64) ? sqn[base0 + 64 + t] : 0.f;
    __syncthreads();
    const short8 bf0 = *(const short8*)((const char*)ej + jl*128 + ((g*16)     ^ ((jl&7)<<4)));
    const short8 bf1 = *(const short8*)((const char*)ej + jl*128 + (((g+4)*16) ^ ((jl&7)<<4)));
    float csum = 0.f;
    for (int it = 0; it < 8; ++it) {
        if (it < 7) {
            char* eib = (char*)ei[(it+1)&1];
            *(short8*)(eib + sb0) = stg0;
            *(short8*)(eib + sb1) = stg1;
            if (t < 64) sqni[(it+1)&1][t] = stgq;
            if (it < 6) {
                const size_t nb = base0 + (size_t)(it+2)*64;
                stg0 = *(const short8*)(emb + (nb + srow0)*FC + sc8*8);
                stg1 = *(const short8*)(emb + (nb + srow1)*FC + sc8*8);
                stgq = (t < 64) ? sqn[nb + t] : 0.f;
            }
        }
        const char* eib = (const char*)ei[it&1];
        const float* sqc = sqni[it&1];
        #pragma unroll
        for (int m = 0; m < 4; ++m) {
            const int arow = m*16 + n16;
            short8 a0 = *(const short8*)(eib + arow*128 + ((g*16)     ^ ((arow&7)<<4)));
            short8 a1 = *(const short8*)(eib + arow*128 + (((g+4)*16) ^ ((arow&7)<<4)));
            f32x4 dot = {0.f,0.f,0.f,0.f};
            dot = MFMA32(a0, bf0, dot);
            dot = MFMA32(a1, bf1, dot);
            #pragma unroll
            for (int r = 0; r < 4; ++r) {
                float x1 = fminf(fmaf(dot[r], 2.f*L2E, fmaf(-L2E, sqc[m*16 + g*4 + r], sqjL)), 0.f);
                float e1 = fexp2(x1);
                float a_ = fmaxf(fmaf(e1, L2E, tjL), 0.f);
                csum += fexp2(a_);
            }
        }
        __syncthreads();
    }
    csum += __shfl_xor(csum, 16);
    csum += __shfl_xor(csum, 32);
    if (lane < 16) atomicAdd(&D[jbase + jl], csum);
}

// ---------------------------------------------------------------------------
// K3: fused score + normalize + PV. grid 512 x 256 (4 waves), 32 rows/block,
// 2 blocks/CU. Correct 1-barrier pipeline, PV(K-1) issued between score(K)
// and transform(K) so PV MFMAs cover the transform's exp2 chain.
// Window K invariants (verified): ej[K&1]=tile K; P[(K-1)&1]=P tile K-1;
// regs: bfC=sct(K-1), scalars=tile K, stg=ej tile K+1.
// ---------------------------------------------------------------------------
#define WIN(K, bfC, bfN, sqC, tC, dC, sqN, tN, dN, DO_PV, DO_STG)              \
  {                                                                            \
    /* a: issue next-tile loads (consumed next window) */                      \
    const int kn = (K) + 1 < 64 ? (K) + 1 : 63;                                \
    sqN = sqn[bbase + (size_t)kn*64 + jl];                                     \
    tN  = T  [bbase + (size_t)kn*64 + jl];                                     \
    dN  = D  [bbase + (size_t)kn*64 + jl];                                     \
    { const short* sb_ = sct2 + ((size_t)(b*64 + (K))*8)*2048                  \
                              + (size_t)(w*64 + n16)*8;                        \
      _Pragma("unroll")                                                        \
      for (int nn = 0; nn < 4; ++nn)                                           \
        _Pragma("unroll")                                                      \
        for (int kc = 0; kc < 2; ++kc)                                         \
          bfN[nn*2+kc] = *(const short8*)(sb_ + (size_t)(kc*4+g)*2048 + nn*128); } \
    /* b: score tile K */                                                      \
    const char* ejb = (const char*)ejlds[(K)&1];                               \
    short8 b0 = *(const short8*)(ejb + jl*128 + ((g*16)     ^ ((jl&7)<<4)));   \
    short8 b1 = *(const short8*)(ejb + jl*128 + (((g+4)*16) ^ ((jl&7)<<4)));   \
    f32x4 dot0 = {0.f,0.f,0.f,0.f}, dot1 = {0.f,0.f,0.f,0.f};                  \
    dot0 = MFMA32(aQ0[0], b0, dot0); dot0 = MFMA32(aQ1[0], b1, dot0);          \
    dot1 = MFMA32(aQ0[1], b0, dot1); dot1 = MFMA32(aQ1[1], b1, dot1);          \
    /* c: PV tile K-1 (independent of score result) */                        \
    if (DO_PV) {                                                               \
      const char* Pb = (const char*)Plds[((K)+1)&1];                           \
      _Pragma("unroll")                                                        \
      for (int m = 0; m < 2; ++m) {                                            \
        const int prow = m*16 + n16;                                           \
        short8 pa0 = *(const short8*)(Pb + prow*128 + (((0*4+g) ^ (prow&7))<<4)); \
        short8 pa1 = *(const short8*)(Pb + prow*128 + (((1*4+g) ^ (prow&7))<<4)); \
        _Pragma("unroll")                                                      \
        for (int nn = 0; nn < 4; ++nn) {                                       \
          acc[m][nn] = MFMA32(pa0, bfC[nn*2+0], acc[m][nn]);                   \
          acc[m][nn] = MFMA32(pa1, bfC[nn*2+1], acc[m][nn]);                   \
        }                                                                      \
      }                                                                        \
    }                                                                          \
    /* e: stage ej tile K+1 -> ej[(K+1)&1]; reload stg <- tile K+2 */          \
    if (DO_STG) {                                                              \
      *(short8*)((char*)ejlds[((K)+1)&1] + sbyte0) = stg0;                     \
      *(short8*)((char*)ejlds[((K)+1)&1] + sbyte1) = stg1;                     \
      if ((K) + 2 < 64) {                                                      \
        stg0 = *(const short8*)(emb + (bbase + (size_t)((K)+2)*64 + srow0)*FC + sc8*8); \
        stg1 = *(const short8*)(emb + (bbase + (size_t)((K)+2)*64 + srow1)*FC + sc8*8); \
      }                                                                        \
    }                                                                          \
    /* d: transform tile K -> P[K&1] */                                        \
    {                                                                          \
      const float iD   = frcp(dC);                                             \
      const float sqjL = -L2E * sqC;                                           \
      const float tjL  = -L2E * tC;                                            \
      char* Pw = (char*)Plds[(K)&1];                                           \
      _Pragma("unroll")                                                        \
      for (int r = 0; r < 4; ++r) {                                            \
        float x1 = fminf(fmaf(dot0[r], 2.f*L2E, snL[0][r] + sqjL), 0.f);       \
        float a_ = fmaxf(fmaf(fexp2(x1), L2E, tjL), 0.f);                      \
        const int prow = g*4 + r;                                              \
        *(short*)(Pw + prow*128 + (((jl>>3) ^ (prow&7))<<4) + (jl&7)*2)        \
            = f2bf(fexp2(a_) * iD);                                            \
      }                                                                        \
      _Pragma("unroll")                                                        \
      for (int r = 0; r < 4; ++r) {                                            \
        float x1 = fminf(fmaf(dot1[r], 2.f*L2E, snL[1][r] + sqjL), 0.f);       \
        float a_ = fmaxf(fmaf(fexp2(x1), L2E, tjL), 0.f);                      \
        const int prow = 16 + g*4 + r;                                         \
        *(short*)(Pw + prow*128 + (((jl>>3) ^ (prow&7))<<4) + (jl&7)*2)        \
            = f2bf(fexp2(a_) * iD);                                            \
      }                                                                        \
    }                                                                          \
    __syncthreads();                                                           \
  }

__global__ __launch_bounds__(256, 2) void k_attn(const float* __restrict__ fm,
    const short* __restrict__ emb, const float* __restrict__ sqn,
    const float* __restrict__ T, const float* __restrict__ D,
    const short* __restrict__ sct2, float* __restrict__ out)
{
    const int bid = ((blockIdx.x & 7) << 6) | (blockIdx.x >> 3);  // 512 blocks
    const int b = bid >> 7;
    const int i0 = (bid & 127) * 32;
    const int t = threadIdx.x, w = t >> 6, lane = t & 63, g = lane >> 4, n16 = lane & 15;
    const size_t bbase = (size_t)b * HW;
    const size_t ibase = bbase + i0;
    __shared__ short ejlds[2][64*64];   // 16 KB
    __shared__ short Plds[2][32*64];    //  8 KB

    const int jl = w*16 + n16;

    // ei fragments (score A-operand side) + per-row norm terms
    short8 aQ0[2], aQ1[2];
    float snL[2][4];
    #pragma unroll
    for (int t2 = 0; t2 < 2; ++t2) {
        const size_t qr = ibase + t2*16 + n16;
        aQ0[t2] = *(const short8*)(emb + qr*FC + g*8);
        aQ1[t2] = *(const short8*)(emb + qr*FC + 32 + g*8);
        #pragma unroll
        for (int r = 0; r < 4; ++r)
            snL[t2][r] = -L2E * sqn[ibase + t2*16 + g*4 + r];
    }
    const int srow0 = t >> 3, srow1 = (t >> 3) + 32, sc8 = t & 7;
    const int sbyte0 = srow0*128 + ((sc8*16) ^ ((srow0&7)<<4));
    const int sbyte1 = srow1*128 + ((sc8*16) ^ ((srow1&7)<<4));

    // prologue: ej[0] <- tile 0; stg <- tile 1; scalars(0) -> A set
    short8 stg0 = *(const short8*)(emb + (bbase + srow0)*FC + sc8*8);
    short8 stg1 = *(const short8*)(emb + (bbase + srow1)*FC + sc8*8);
    *(short8*)((char*)ejlds[0] + sbyte0) = stg0;
    *(short8*)((char*)ejlds[0] + sbyte1) = stg1;
    stg0 = *(const short8*)(emb + (bbase + 64 + srow0)*FC + sc8*8);
    stg1 = *(const short8*)(emb + (bbase + 64 + srow1)*FC + sc8*8);
    float sqA = sqn[bbase + jl], tA = T[bbase + jl], dA = D[bbase + jl];
    float sqB, tB, dB;
    short8 bfA[8], bfB[8];
    f32x4 acc[2][4];
    #pragma unroll
    for (int m = 0; m < 2; ++m)
        #pragma unroll
        for (int nn = 0; nn < 4; ++nn) acc[m][nn] = (f32x4){0.f,0.f,0.f,0.f};
    __syncthreads();            // ej[0] visible

    // W0: score tile0 (scalars A), load bf(0)->bfA, no PV
    WIN(0, bfB, bfA, sqA, tA, dA, sqB, tB, dB, 0, 1)
    // W1..W62 in pairs; odd K: PV uses bfA/scalars B; even K: bfB/scalars A
    for (int k = 1; k < 62; k += 2) {
        WIN(k,   bfA, bfB, sqB, tB, dB, sqA, tA, dA, 1, 1)
        WIN(k+1, bfB, bfA, sqA, tA, dA, sqB, tB, dB, 1, 1)
    }
    // W63 (odd): PV(62) with bfA, score tile63 (scalars B), load bf(63)->bfB
    WIN(63, bfA, bfB, sqB, tB, dB, sqA, tA, dA, 1, 0)

    // epilogue: PV tile 63 from P[1], bfB
    {
        const char* Pb = (const char*)Plds[1];
        #pragma unroll
        for (int m = 0; m < 2; ++m) {
            const int prow = m*16 + n16;
            short8 pa0 = *(const short8*)(Pb + prow*128 + (((0*4+g) ^ (prow&7))<<4));
            short8 pa1 = *(const short8*)(Pb + prow*128 + (((1*4+g) ^ (prow&7))<<4));
            #pragma unroll
            for (int nn = 0; nn < 4; ++nn) {
                acc[m][nn] = MFMA32(pa0, bfB[nn*2+0], acc[m][nn]);
                acc[m][nn] = MFMA32(pa1, bfB[nn*2+1], acc[m][nn]);
            }
        }
    }

    #pragma unroll
    for (int m = 0; m < 2; ++m)
        #pragma unroll
        for (int r = 0; r < 4; ++r) {
            const size_t row = ibase + m*16 + g*4 + r;
            #pragma unroll
            for (int nn = 0; nn < 4; ++nn) {
                const size_t idx = row*CC + w*64 + nn*16 + n16;
                out[idx] = fm[idx] + acc[m][nn][r];
            }
        }
}

extern "C" void kernel_launch(void* const* d_in, const int* in_sizes, int n_in,
                              void* d_out, int out_size, void* d_ws, size_t ws_size,
                              hipStream_t stream)
{
    const float* fm   = (const float*)d_in[0];
    const float* Wemb = (const float*)d_in[1];
    const float* bemb = (const float*)d_in[2];
    const float* Watt = (const float*)d_in[3];
    const float* batt = (const float*)d_in[4];
    const float* Wthr = (const float*)d_in[5];
    const float* bthr = (const float*)d_in[6];
    char* ws = (char*)d_ws;
    short* emb   = (short*)(ws + OFF_EMB);
    short* sct2  = (short*)(ws + OFF_SCT2);
    float* sqn   = (float*)(ws + OFF_SQN);
    float* T     = (float*)(ws + OFF_T);
    float* D     = (float*)(ws + OFF_D);
    short* Wemb2 = (short*)(ws + OFF_WEMB2);
    short* Watt2 = (short*)(ws + OFF_WATT2);
    float* out = (float*)d_out;

    k_prep  <<<320,  256, 0, stream>>>(Wemb, Watt, Wemb2, Watt2, D);
    k_front <<<1024, 256, 0, stream>>>(fm, Wemb2, Watt2, bemb, batt, Wthr, bthr,
                                       emb, sct2, sqn, T);
    k_colsum<<<2048, 256, 0, stream>>>(emb, sqn, T, D);
    k_attn  <<<512,  256, 0, stream>>>(fm, emb, sqn, T, D, sct2, out);
}

// Round 9
// 106.665 us; speedup vs baseline: 1.7057x; 1.0329x over previous
//
#include <hip/hip_runtime.h>
#include <hip/hip_bf16.h>
#include <math.h>

typedef __attribute__((ext_vector_type(8))) short short8;
typedef __attribute__((ext_vector_type(4))) float f32x4;

#define BB 4
#define HW 4096
#define CC 256
#define FC 64
#define L2E 1.4426950408889634f

// ws byte offsets
#define OFF_EMB   0                      // short[16384*64]   = 2 MB
#define OFF_SCT2  (2*1024*1024)          // short[4*64*8*256*8] = 8 MB
#define OFF_SQN   (OFF_SCT2 + 8*1024*1024)
#define OFF_T     (OFF_SQN + 65536)
#define OFF_D     (OFF_T   + 65536)
#define OFF_WEMB2 (OFF_D   + 65536)      // short[32*64*8] = 32 KB
#define OFF_WATT2 (OFF_WEMB2 + 32768)    // short[32*256*8] = 128 KB

static __device__ __forceinline__ short f2bf(float f) {
    __hip_bfloat16 h = __float2bfloat16(f);
    return *reinterpret_cast<short*>(&h);
}
static __device__ __forceinline__ float bf2f(short s) {
    __hip_bfloat16 h = *reinterpret_cast<__hip_bfloat16*>(&s);
    return __bfloat162float(h);
}
static __device__ __forceinline__ float fexp2(float x) {
#if __has_builtin(__builtin_amdgcn_exp2f)
    return __builtin_amdgcn_exp2f(x);
#else
    float r; asm("v_exp_f32 %0, %1" : "=v"(r) : "v"(x)); return r;
#endif
}
static __device__ __forceinline__ float frcp(float x) {
#if __has_builtin(__builtin_amdgcn_rcpf)
    return __builtin_amdgcn_rcpf(x);
#else
    return 1.0f / x;
#endif
}
#define MFMA32(a, b, c) __builtin_amdgcn_mfma_f32_16x16x32_bf16(a, b, c, 0, 0, 0)

// ---------------------------------------------------------------------------
// K0: weight conversion to tiled bf16 B-fragment layouts + D zero.
// ---------------------------------------------------------------------------
__global__ __launch_bounds__(256) void k_prep(const float* __restrict__ Wemb,
    const float* __restrict__ Watt, short* __restrict__ Wemb2,
    short* __restrict__ Watt2, float* __restrict__ D)
{
    const int bid = blockIdx.x, t = threadIdx.x;
    if (bid < 256) {
        Watt2[(size_t)(t>>3)*2048 + bid*8 + (t&7)] = f2bf(Watt[(size_t)bid*256 + t]);
        if (bid < 64) D[bid*256 + t] = 0.f;
    } else {
        const int f = bid - 256;
        Wemb2[(size_t)(t>>3)*512 + f*8 + (t&7)] = f2bf(Wemb[(size_t)f*256 + t]);
    }
}

// ---------------------------------------------------------------------------
// K1 (fused emb + shortcut + threshold, all MFMA). grid 1024 x 256.
// ---------------------------------------------------------------------------
__global__ __launch_bounds__(256) void k_front(const float* __restrict__ fm,
    const short* __restrict__ Wemb2, const short* __restrict__ Watt2,
    const float* __restrict__ bemb, const float* __restrict__ batt,
    const float* __restrict__ wthr, const float* __restrict__ bthr,
    short* __restrict__ emb, short* __restrict__ sct2,
    float* __restrict__ sqn, float* __restrict__ T)
{
    const int blk = blockIdx.x;
    const int b = blk >> 8;
    const int r0 = (blk & 255) * 16;
    const int t = threadIdx.x;
    const int w = t >> 6, lane = t & 63, g = lane >> 4, n16 = lane & 15;
    __shared__ short fmt[16*256];
    __shared__ float tred[16][4];
    __shared__ float qred[16][4];
    #pragma unroll
    for (int v = t; v < 512; v += 256) {
        const int row = v >> 5, c32 = v & 31;
        const float4* src = (const float4*)(fm + ((size_t)b*HW + r0 + row)*CC + c32*8);
        float4 x0 = src[0], x1 = src[1];
        short8 pv;
        pv[0]=f2bf(x0.x); pv[1]=f2bf(x0.y); pv[2]=f2bf(x0.z); pv[3]=f2bf(x0.w);
        pv[4]=f2bf(x1.x); pv[5]=f2bf(x1.y); pv[6]=f2bf(x1.z); pv[7]=f2bf(x1.w);
        *(short8*)((char*)fmt + row*512 + ((c32*16) ^ ((row&7)<<4))) = pv;
    }
    __syncthreads();
    const int cb = w*64, fb = w*16;
    f32x4 acc[4], acce;
    #pragma unroll
    for (int nn = 0; nn < 4; ++nn) acc[nn] = (f32x4){0.f,0.f,0.f,0.f};
    acce = (f32x4){0.f,0.f,0.f,0.f};
    #pragma unroll
    for (int kk = 0; kk < 8; ++kk) {
        const int kc = kk*4 + g;
        short8 a = *(const short8*)((const char*)fmt + n16*512 + ((kc*16) ^ ((n16&7)<<4)));
        const short* wb = Watt2 + (size_t)kc*2048 + (cb + n16)*8;
        #pragma unroll
        for (int nn = 0; nn < 4; ++nn) {
            short8 bv = *(const short8*)(wb + nn*128);
            acc[nn] = MFMA32(a, bv, acc[nn]);
        }
        short8 be = *(const short8*)(Wemb2 + (size_t)kc*512 + (fb + n16)*8);
        acce = MFMA32(a, be, acce);
    }
    float tp[4] = {0.f,0.f,0.f,0.f};
    const int jt_ = r0 >> 6;
    const int jc0 = (r0 & 63) >> 3;
    const size_t tilebase = ((size_t)b*64 + jt_)*8;
    #pragma unroll
    for (int nn = 0; nn < 4; ++nn) {
        const int ch = cb + nn*16 + n16;
        const float ba_ = batt[ch], wt_ = wthr[ch];
        float v[4];
        #pragma unroll
        for (int r = 0; r < 4; ++r) { v[r] = acc[nn][r] + ba_; tp[r] = fmaf(v[r], wt_, tp[r]); }
        const int jc = jc0 + (g >> 1);
        const int jw0 = (g & 1)*4;
        short* dstp = sct2 + (tilebase + jc)*2048 + (size_t)ch*8;
        unsigned u01 = (unsigned short)f2bf(v[0]) | ((unsigned)(unsigned short)f2bf(v[1]) << 16);
        unsigned u23 = (unsigned short)f2bf(v[2]) | ((unsigned)(unsigned short)f2bf(v[3]) << 16);
        *(unsigned*)(dstp + jw0)     = u01;
        *(unsigned*)(dstp + jw0 + 2) = u23;
    }
    #pragma unroll
    for (int r = 0; r < 4; ++r)
        #pragma unroll
        for (int off = 1; off <= 8; off <<= 1) tp[r] += __shfl_xor(tp[r], off);
    const int f = fb + n16;
    const float be_ = bemb[f];
    float qp[4];
    #pragma unroll
    for (int r = 0; r < 4; ++r) {
        short bv = f2bf(acce[r] + be_);
        emb[((size_t)b*HW + r0 + g*4 + r)*FC + f] = bv;
        float ef = bf2f(bv);
        qp[r] = ef*ef;
        #pragma unroll
        for (int off = 1; off <= 8; off <<= 1) qp[r] += __shfl_xor(qp[r], off);
    }
    if (n16 == 0) {
        #pragma unroll
        for (int r = 0; r < 4; ++r) { tred[g*4+r][w] = tp[r]; qred[g*4+r][w] = qp[r]; }
    }
    __syncthreads();
    if (t < 16) {
        T[(size_t)b*HW + r0 + t]   = tred[t][0]+tred[t][1]+tred[t][2]+tred[t][3] + bthr[0];
        sqn[(size_t)b*HW + r0 + t] = qred[t][0]+qred[t][1]+qred[t][2]+qred[t][3];
    }
}

// ---------------------------------------------------------------------------
// K2: column sums D[j]. grid 2048 x 256. 1 barrier/iter, dbuf ei.
// ---------------------------------------------------------------------------
__global__ __launch_bounds__(256) void k_colsum(const short* __restrict__ emb,
    const float* __restrict__ sqn, const float* __restrict__ T,
    float* __restrict__ D)
{
    const int bid = blockIdx.x;
    const int split = bid & 7, jt = (bid >> 3) & 63, b = bid >> 9;
    const int t = threadIdx.x, w = t >> 6, lane = t & 63, g = lane >> 4, n16 = lane & 15;
    const size_t jbase = (size_t)b*HW + jt*64;
    __shared__ short ej[64*64];
    __shared__ short ei[2][64*64];
    __shared__ float sqni[2][64];
    #pragma unroll
    for (int v = t; v < 512; v += 256) {
        const int row = v >> 3, c8 = v & 7;
        short8 x = *(const short8*)(emb + (jbase + row)*FC + c8*8);
        *(short8*)((char*)ej + row*128 + ((c8*16) ^ ((row&7)<<4))) = x;
    }
    const int jl = w*16 + n16;
    const float sqjL = -L2E * sqn[jbase + jl];
    const float tjL  = -L2E * T[jbase + jl];
    const int srow0 = t >> 3, srow1 = (t >> 3) + 32, sc8 = t & 7;
    const int sb0 = srow0*128 + ((sc8*16) ^ ((srow0&7)<<4));
    const int sb1 = srow1*128 + ((sc8*16) ^ ((srow1&7)<<4));
    const size_t base0 = (size_t)b*HW + (size_t)split*512;
    short8 stg0 = *(const short8*)(emb + (base0 + srow0)*FC + sc8*8);
    short8 stg1 = *(const short8*)(emb + (base0 + srow1)*FC + sc8*8);
    float stgq = (t < 64) ? sqn[base0 + t] : 0.f;
    *(short8*)((char*)ei[0] + sb0) = stg0;
    *(short8*)((char*)ei[0] + sb1) = stg1;
    if (t < 64) sqni[0][t] = stgq;
    stg0 = *(const short8*)(emb + (base0 + 64 + srow0)*FC + sc8*8);
    stg1 = *(const short8*)(emb + (base0 + 64 + srow1)*FC + sc8*8);
    stgq = (t < 64) ? sqn[base0 + 64 + t] : 0.f;
    __syncthreads();
    const short8 bf0 = *(const short8*)((const char*)ej + jl*128 + ((g*16)     ^ ((jl&7)<<4)));
    const short8 bf1 = *(const short8*)((const char*)ej + jl*128 + (((g+4)*16) ^ ((jl&7)<<4)));
    float csum = 0.f;
    for (int it = 0; it < 8; ++it) {
        if (it < 7) {
            char* eib = (char*)ei[(it+1)&1];
            *(short8*)(eib + sb0) = stg0;
            *(short8*)(eib + sb1) = stg1;
            if (t < 64) sqni[(it+1)&1][t] = stgq;
            if (it < 6) {
                const size_t nb = base0 + (size_t)(it+2)*64;
                stg0 = *(const short8*)(emb + (nb + srow0)*FC + sc8*8);
                stg1 = *(const short8*)(emb + (nb + srow1)*FC + sc8*8);
                stgq = (t < 64) ? sqn[nb + t] : 0.f;
            }
        }
        const char* eib = (const char*)ei[it&1];
        const float* sqc = sqni[it&1];
        #pragma unroll
        for (int m = 0; m < 4; ++m) {
            const int arow = m*16 + n16;
            short8 a0 = *(const short8*)(eib + arow*128 + ((g*16)     ^ ((arow&7)<<4)));
            short8 a1 = *(const short8*)(eib + arow*128 + (((g+4)*16) ^ ((arow&7)<<4)));
            f32x4 dot = {0.f,0.f,0.f,0.f};
            dot = MFMA32(a0, bf0, dot);
            dot = MFMA32(a1, bf1, dot);
            #pragma unroll
            for (int r = 0; r < 4; ++r) {
                float x1 = fminf(fmaf(dot[r], 2.f*L2E, fmaf(-L2E, sqc[m*16 + g*4 + r], sqjL)), 0.f);
                float e1 = fexp2(x1);
                float a_ = fmaxf(fmaf(e1, L2E, tjL), 0.f);
                csum += fexp2(a_);
            }
        }
        __syncthreads();
    }
    csum += __shfl_xor(csum, 16);
    csum += __shfl_xor(csum, 32);
    if (lane < 16) atomicAdd(&D[jbase + jl], csum);
}

// ---------------------------------------------------------------------------
// K3: fused score + normalize + PV. grid 256 x 512 (8 waves), 64 rows/block,
// DOUBLE-WIDTH windows: one barrier per 2 j-tiles (32 barriers total).
// wave w: ih = w&1 (i-half for score), jq = w>>1 (j-quarter);
//         PV channels w*32..+31 x all 64 rows (acc[4][2], 16 MFMA/tile).
// LDS: ej pair-dbuf 32KB + P pair-dbuf 32KB = 64KB (correctly sized).
// Window W (tiles K0=2W, K1=2W+1):
//   loads(pair W+1) | score+transform K0,K1 -> P[W&1] | stage ej pair W+1
//   -> E[(W+1)&1] | barrier | setprio(1) PV K0,K1 (bfC pair) setprio(0)
// ---------------------------------------------------------------------------
#define SCORE_XF(TT, EJB, PW, SQ, TJ, DD)                                      \
  {                                                                            \
    const char* ejb_ = (EJB) + (TT)*8192;                                      \
    short8 b0 = *(const short8*)(ejb_ + jl*128 + ((g*16)     ^ ((jl&7)<<4)));  \
    short8 b1 = *(const short8*)(ejb_ + jl*128 + (((g+4)*16) ^ ((jl&7)<<4)));  \
    const float iD   = frcp(DD);                                               \
    const float sqjL = -L2E * (SQ);                                            \
    const float tjL  = -L2E * (TJ);                                            \
    _Pragma("unroll")                                                          \
    for (int t2 = 0; t2 < 2; ++t2) {                                           \
      f32x4 dot = {0.f,0.f,0.f,0.f};                                           \
      dot = MFMA32(aQ0[t2], b0, dot);                                          \
      dot = MFMA32(aQ1[t2], b1, dot);                                          \
      _Pragma("unroll")                                                        \
      for (int r = 0; r < 4; ++r) {                                            \
        float x1 = fminf(fmaf(dot[r], 2.f*L2E, snL[t2][r] + sqjL), 0.f);       \
        float a_ = fmaxf(fmaf(fexp2(x1), L2E, tjL), 0.f);                      \
        const int prow = ih*32 + t2*16 + g*4 + r;                              \
        *(short*)((PW) + (TT)*8192 + prow*128                                  \
                  + (((jl>>3) ^ (prow&7))<<4) + (jl&7)*2)                      \
            = f2bf(fexp2(a_) * iD);                                            \
      }                                                                        \
    }                                                                          \
  }

#define PV_TILE(TT, PB, BF)                                                    \
  { _Pragma("unroll")                                                          \
    for (int m = 0; m < 4; ++m) {                                              \
      const int prow = m*16 + n16;                                             \
      short8 pa0 = *(const short8*)((PB) + (TT)*8192 + prow*128                \
                                    + (((0*4+g) ^ (prow&7))<<4));              \
      short8 pa1 = *(const short8*)((PB) + (TT)*8192 + prow*128                \
                                    + (((1*4+g) ^ (prow&7))<<4));              \
      _Pragma("unroll")                                                        \
      for (int nn = 0; nn < 2; ++nn) {                                         \
        acc[m][nn] = MFMA32(pa0, (BF)[nn*2+0], acc[m][nn]);                    \
        acc[m][nn] = MFMA32(pa1, (BF)[nn*2+1], acc[m][nn]);                    \
      }                                                                        \
    } }

#define LOAD_BF(DST, TILE)                                                     \
  { const short* sb_ = sct2 + ((size_t)(b*64 + (TILE))*8)*2048                 \
                            + (size_t)(w*32 + n16)*8;                          \
    _Pragma("unroll")                                                          \
    for (int nn = 0; nn < 2; ++nn)                                             \
      _Pragma("unroll")                                                        \
      for (int kc = 0; kc < 2; ++kc)                                           \
        (DST)[nn*2+kc] = *(const short8*)(sb_ + (size_t)(kc*4+g)*2048 + nn*128); }

#define WIN(W, q0C,t0C,d0C, q1C,t1C,d1C, bf0C,bf1C,                            \
            q0N,t0N,d0N, q1N,t1N,d1N, bf0N,bf1N)                               \
  {                                                                            \
    const int k0n = (2*(W)+2 < 64) ? 2*(W)+2 : 63;                             \
    const int k1n = (2*(W)+3 < 64) ? 2*(W)+3 : 63;                             \
    q0N = sqn[bbase + (size_t)k0n*64 + jl];                                    \
    t0N = T  [bbase + (size_t)k0n*64 + jl];                                    \
    d0N = D  [bbase + (size_t)k0n*64 + jl];                                    \
    q1N = sqn[bbase + (size_t)k1n*64 + jl];                                    \
    t1N = T  [bbase + (size_t)k1n*64 + jl];                                    \
    d1N = D  [bbase + (size_t)k1n*64 + jl];                                    \
    LOAD_BF(bf0N, k0n)                                                         \
    LOAD_BF(bf1N, k1n)                                                         \
    const char* Eb = (const char*)ejlds[(W)&1];                                \
    char* Pw = (char*)Plds[(W)&1];                                             \
    SCORE_XF(0, Eb, Pw, q0C, t0C, d0C)                                         \
    SCORE_XF(1, Eb, Pw, q1C, t1C, d1C)                                         \
    { char* En = (char*)ejlds[((W)+1)&1];                                      \
      *(short8*)(En + sbyte) = stgA;                                           \
      *(short8*)(En + 8192 + sbyte) = stgB;                                    \
      const int k0s = (2*(W)+4 < 64) ? 2*(W)+4 : 63;                           \
      const int k1s = (2*(W)+5 < 64) ? 2*(W)+5 : 63;                           \
      stgA = *(const short8*)(emb + (bbase + (size_t)k0s*64 + srow)*FC + sc8*8); \
      stgB = *(const short8*)(emb + (bbase + (size_t)k1s*64 + srow)*FC + sc8*8); \
    }                                                                          \
    __syncthreads();                                                           \
    const char* Pb = (const char*)Plds[(W)&1];                                 \
    __builtin_amdgcn_s_setprio(1);                                             \
    PV_TILE(0, Pb, bf0C)                                                       \
    PV_TILE(1, Pb, bf1C)                                                       \
    __builtin_amdgcn_s_setprio(0);                                             \
  }

__global__ __launch_bounds__(512, 2) void k_attn(const float* __restrict__ fm,
    const short* __restrict__ emb, const float* __restrict__ sqn,
    const float* __restrict__ T, const float* __restrict__ D,
    const short* __restrict__ sct2, float* __restrict__ out)
{
    const int bid = ((blockIdx.x & 7) << 5) | (blockIdx.x >> 3);  // 256 blocks
    const int b = bid >> 6;
    const int i0 = (bid & 63) * 64;
    const int t = threadIdx.x, w = t >> 6, lane = t & 63, g = lane >> 4, n16 = lane & 15;
    const size_t bbase = (size_t)b * HW;
    const size_t ibase = bbase + i0;
    __shared__ short ejlds[2][2*64*64];   // 2 pair-bufs x 16KB = 32 KB
    __shared__ short Plds[2][2*64*64];    // 2 pair-bufs x 16KB = 32 KB

    const int ih = w & 1, jq = w >> 1;
    const int jl = jq*16 + n16;

    // score A-operand fragments (ei rows of this wave's i-half) + norms
    short8 aQ0[2], aQ1[2];
    float snL[2][4];
    #pragma unroll
    for (int t2 = 0; t2 < 2; ++t2) {
        const size_t qr = ibase + ih*32 + t2*16 + n16;
        aQ0[t2] = *(const short8*)(emb + qr*FC + g*8);
        aQ1[t2] = *(const short8*)(emb + qr*FC + 32 + g*8);
        #pragma unroll
        for (int r = 0; r < 4; ++r)
            snL[t2][r] = -L2E * sqn[ibase + ih*32 + t2*16 + g*4 + r];
    }
    const int srow = t >> 3, sc8 = t & 7;
    const int sbyte = srow*128 + ((sc8*16) ^ ((srow&7)<<4));

    // prologue: stage pair 0 -> E[0]; stg <- pair 1; scalars+bf pair0 -> A
    short8 stgA = *(const short8*)(emb + (bbase + srow)*FC + sc8*8);
    short8 stgB = *(const short8*)(emb + (bbase + 64 + srow)*FC + sc8*8);
    *(short8*)((char*)ejlds[0] + sbyte) = stgA;
    *(short8*)((char*)ejlds[0] + 8192 + sbyte) = stgB;
    stgA = *(const short8*)(emb + (bbase + 128 + srow)*FC + sc8*8);
    stgB = *(const short8*)(emb + (bbase + 192 + srow)*FC + sc8*8);
    float q0A = sqn[bbase + jl],      t0A = T[bbase + jl],      d0A = D[bbase + jl];
    float q1A = sqn[bbase + 64 + jl], t1A = T[bbase + 64 + jl], d1A = D[bbase + 64 + jl];
    float q0B, t0B, d0B, q1B, t1B, d1B;
    short8 bf0A[4], bf1A[4], bf0B[4], bf1B[4];
    LOAD_BF(bf0A, 0)
    LOAD_BF(bf1A, 1)
    f32x4 acc[4][2];
    #pragma unroll
    for (int m = 0; m < 4; ++m) {
        acc[m][0] = (f32x4){0.f,0.f,0.f,0.f};
        acc[m][1] = (f32x4){0.f,0.f,0.f,0.f};
    }
    __syncthreads();            // E[0] visible

    for (int w2 = 0; w2 < 32; w2 += 2) {
        WIN(w2,   q0A,t0A,d0A, q1A,t1A,d1A, bf0A,bf1A,
                  q0B,t0B,d0B, q1B,t1B,d1B, bf0B,bf1B)
        WIN(w2+1, q0B,t0B,d0B, q1B,t1B,d1B, bf0B,bf1B,
                  q0A,t0A,d0A, q1A,t1A,d1A, bf0A,bf1A)
    }

    #pragma unroll
    for (int m = 0; m < 4; ++m)
        #pragma unroll
        for (int r = 0; r < 4; ++r) {
            const size_t row = ibase + m*16 + g*4 + r;
            #pragma unroll
            for (int nn = 0; nn < 2; ++nn) {
                const size_t idx = row*CC + w*32 + nn*16 + n16;
                out[idx] = fm[idx] + acc[m][nn][r];
            }
        }
}

extern "C" void kernel_launch(void* const* d_in, const int* in_sizes, int n_in,
                              void* d_out, int out_size, void* d_ws, size_t ws_size,
                              hipStream_t stream)
{
    const float* fm   = (const float*)d_in[0];
    const float* Wemb = (const float*)d_in[1];
    const float* bemb = (const float*)d_in[2];
    const float* Watt = (const float*)d_in[3];
    const float* batt = (const float*)d_in[4];
    const float* Wthr = (const float*)d_in[5];
    const float* bthr = (const float*)d_in[6];
    char* ws = (char*)d_ws;
    short* emb   = (short*)(ws + OFF_EMB);
    short* sct2  = (short*)(ws + OFF_SCT2);
    float* sqn   = (float*)(ws + OFF_SQN);
    float* T     = (float*)(ws + OFF_T);
    float* D     = (float*)(ws + OFF_D);
    short* Wemb2 = (short*)(ws + OFF_WEMB2);
    short* Watt2 = (short*)(ws + OFF_WATT2);
    float* out = (float*)d_out;

    k_prep  <<<320,  256, 0, stream>>>(Wemb, Watt, Wemb2, Watt2, D);
    k_front <<<1024, 256, 0, stream>>>(fm, Wemb2, Watt2, bemb, batt, Wthr, bthr,
                                       emb, sct2, sqn, T);
    k_colsum<<<2048, 256, 0, stream>>>(emb, sqn, T, D);
    k_attn  <<<256,  512, 0, stream>>>(fm, emb, sqn, T, D, sct2, out);
}